// Round 1
// 207.506 us; speedup vs baseline: 1.0126x; 1.0126x over previous
//
#include <hip/hip_runtime.h>
#include <math.h>
#include <stdint.h>

// Problem constants (match reference)
#define BG 256   // graphs
#define NN 512   // nodes per graph
#define DD 256   // feature dim
#define KK 256   // nodes kept per graph
#define WAVES 8  // waves per block (512 threads)
#define ROWS_W (NN / WAVES)        // 64 rows per wave
#define LDSR_W 16                  // rows per wave staged to LDS
#define REGR_W (ROWS_W - LDSR_W)   // 48 rows retained in VGPRs

// ---------------------------------------------------------------------------
// Single-pass TopKPooling + global_mean_pool: x is read from HBM exactly ONCE.
//
// One block (512 thr, 8 waves) per graph = 1 block/CU. Wave w owns rows
// [64w, 64w+64): during the score pass it stages its first 16 rows to LDS
// (8 waves x 16 rows x 1 KiB = 128 KiB) and RETAINS the other 48 rows in
// registers (192 VGPRs; __launch_bounds__(512,2) gives the 256-VGPR budget).
//
// Selection ranks RAW dot products (tanh and the positive 1/||w|| scale are
// strictly monotonic -> identical top-K set + identical index tie-breaks).
// tanhf is applied once per node at gate time, off the streaming path.
//
// Every wave runs the exact radix select redundantly on the shared score
// array (ballot/popc, ~1 us) and writes gate values g[i] = sel ? tanh/K : 0
// for its OWN 64 nodes -> phase 3 needs no barrier and no index lists:
// acc += g[i] * row_i over rows already in regs/LDS. Zero global re-reads,
// 2 barriers total.
// ---------------------------------------------------------------------------
__device__ __forceinline__ uint32_t flip_f32(float f) {
    const uint32_t u = __float_as_uint(f);
    return (u & 0x80000000u) ? ~u : (u | 0x80000000u);   // order-preserving map
}
__device__ __forceinline__ float unflip_f32(uint32_t u) {
    return __uint_as_float((u & 0x80000000u) ? (u ^ 0x80000000u) : ~u);
}

__global__ __launch_bounds__(512, 2) void topk_pool_fused(const float* __restrict__ x,
                                                          const float* __restrict__ w,
                                                          float* __restrict__ out) {
    __shared__ float xs[WAVES * LDSR_W][DD];  // 128 KiB staged rows
    __shared__ float s[NN];                   // raw scores (pre-norm, pre-tanh)
    __shared__ float g[NN];                   // per-node gate = sel * tanh / K
    __shared__ float red[WAVES][DD];          // 8 KiB cross-wave reduction

    const int b    = blockIdx.x;
    const int wv   = threadIdx.x >> 6;
    const int lane = threadIdx.x & 63;

    const float4 w4 = *reinterpret_cast<const float4*>(w + lane * 4);
    float nw = fmaf(w4.x, w4.x, fmaf(w4.y, w4.y, fmaf(w4.z, w4.z, w4.w * w4.w)));
#pragma unroll
    for (int off = 32; off >= 1; off >>= 1) nw += __shfl_xor(nw, off);
    const float inv_nrm = rsqrtf(nw);

    const float* xg = x + (size_t)b * NN * DD;
    const int r0 = wv * ROWS_W;                       // first node of this wave
    const float* xp = xg + (size_t)r0 * DD + lane * 4;

    // ------------- Phase 1a: rows [r0, r0+16) -> dots + stage to LDS -------
#pragma unroll
    for (int bt = 0; bt < LDSR_W / 8; ++bt) {
        float4 a[8];
        float  d[8];
#pragma unroll
        for (int j = 0; j < 8; ++j)
            a[j] = *reinterpret_cast<const float4*>(xp + (size_t)(bt * 8 + j) * DD);
#pragma unroll
        for (int j = 0; j < 8; ++j)
            d[j] = fmaf(a[j].x, w4.x, fmaf(a[j].y, w4.y, fmaf(a[j].z, w4.z, a[j].w * w4.w)));
#pragma unroll
        for (int off = 32; off >= 1; off >>= 1) {
#pragma unroll
            for (int j = 0; j < 8; ++j) d[j] += __shfl_xor(d[j], off);
        }
#pragma unroll
        for (int j = 0; j < 8; ++j)
            *reinterpret_cast<float4*>(&xs[wv * LDSR_W + bt * 8 + j][lane * 4]) = a[j];
        if (lane == 0) {
            float4 o0 = {d[0], d[1], d[2], d[3]};
            float4 o1 = {d[4], d[5], d[6], d[7]};
            *reinterpret_cast<float4*>(&s[r0 + bt * 8])     = o0;
            *reinterpret_cast<float4*>(&s[r0 + bt * 8 + 4]) = o1;
        }
    }

    // ------------- Phase 1b: rows [r0+16, r0+64) -> dots + RETAIN in regs --
    float4 h[REGR_W];
#pragma unroll
    for (int bt = 0; bt < REGR_W / 8; ++bt) {
        float d[8];
#pragma unroll
        for (int j = 0; j < 8; ++j)
            h[bt * 8 + j] = *reinterpret_cast<const float4*>(xp + (size_t)(LDSR_W + bt * 8 + j) * DD);
#pragma unroll
        for (int j = 0; j < 8; ++j) {
            const float4 a = h[bt * 8 + j];
            d[j] = fmaf(a.x, w4.x, fmaf(a.y, w4.y, fmaf(a.z, w4.z, a.w * w4.w)));
        }
#pragma unroll
        for (int off = 32; off >= 1; off >>= 1) {
#pragma unroll
            for (int j = 0; j < 8; ++j) d[j] += __shfl_xor(d[j], off);
        }
        if (lane == 0) {
            float4 o0 = {d[0], d[1], d[2], d[3]};
            float4 o1 = {d[4], d[5], d[6], d[7]};
            *reinterpret_cast<float4*>(&s[r0 + LDSR_W + bt * 8])     = o0;
            *reinterpret_cast<float4*>(&s[r0 + LDSR_W + bt * 8 + 4]) = o1;
        }
    }
    __syncthreads();

    // ------------- Phase 2: exact top-K radix select (redundant per wave) --
    {
        const float4 a0 = *reinterpret_cast<const float4*>(&s[lane * 8]);
        const float4 a1 = *reinterpret_cast<const float4*>(&s[lane * 8 + 4]);
        uint32_t u[8];
        u[0] = flip_f32(a0.x); u[1] = flip_f32(a0.y); u[2] = flip_f32(a0.z); u[3] = flip_f32(a0.w);
        u[4] = flip_f32(a1.x); u[5] = flip_f32(a1.y); u[6] = flip_f32(a1.z); u[7] = flip_f32(a1.w);

        // MSB-first binary search: p ends as the exact K-th largest key.
        uint32_t p = 0u;
        for (int bit = 31; bit >= 0; --bit) {
            const uint32_t cand = p | (1u << bit);
            int cnt = 0;
#pragma unroll
            for (int j = 0; j < 8; ++j)
                cnt += __popcll(__ballot(u[j] >= cand));
            if (cnt >= KK) p = cand;
        }

        unsigned long long bt8[8];
        int cgt = 0;
#pragma unroll
        for (int j = 0; j < 8; ++j) {
            cgt += __popcll(__ballot(u[j] > p));
            bt8[j] = __ballot(u[j] == p);
        }
        const int need = KK - cgt;   // ties at p to take, lowest node index first
        const unsigned long long below = ((unsigned long long)1 << lane) - 1ull;

        int tie_rank = 0;
#pragma unroll
        for (int j = 0; j < 8; ++j) tie_rank += __popcll(bt8[j] & below);

        float gv[8];
        int ntie = 0;
#pragma unroll
        for (int j = 0; j < 8; ++j) {
            const bool tie = (u[j] == p);
            const bool sel = (u[j] > p) || (tie && (tie_rank + ntie) < need);
            // tanh + norm-scale only here (once per node, off the BW path)
            gv[j] = sel ? tanhf(unflip_f32(u[j]) * inv_nrm) * (1.0f / (float)KK) : 0.0f;
            ntie += tie ? 1 : 0;
        }

        // Each wave writes gates for ITS OWN 64 nodes (lanes 8w..8w+8 hold
        // them) -> phase 3 reads only same-wave LDS writes: no barrier.
        if ((lane >> 3) == wv) {
            float4 g0 = {gv[0], gv[1], gv[2], gv[3]};
            float4 g1 = {gv[4], gv[5], gv[6], gv[7]};
            *reinterpret_cast<float4*>(&g[lane * 8])     = g0;
            *reinterpret_cast<float4*>(&g[lane * 8 + 4]) = g1;
        }
    }

    // ------------- Phase 3: gated accumulate from LDS + registers ----------
    float4 acc = {0.f, 0.f, 0.f, 0.f};
#pragma unroll
    for (int j = 0; j < LDSR_W; ++j) {
        const float gj = g[r0 + j];
        const float4 v = *reinterpret_cast<const float4*>(&xs[wv * LDSR_W + j][lane * 4]);
        acc.x = fmaf(gj, v.x, acc.x);
        acc.y = fmaf(gj, v.y, acc.y);
        acc.z = fmaf(gj, v.z, acc.z);
        acc.w = fmaf(gj, v.w, acc.w);
    }
#pragma unroll
    for (int q = 0; q < REGR_W; ++q) {
        const float gq = g[r0 + LDSR_W + q];
        acc.x = fmaf(gq, h[q].x, acc.x);
        acc.y = fmaf(gq, h[q].y, acc.y);
        acc.z = fmaf(gq, h[q].z, acc.z);
        acc.w = fmaf(gq, h[q].w, acc.w);
    }
    *reinterpret_cast<float4*>(&red[wv][lane * 4]) = acc;
    __syncthreads();

    if (threadIdx.x < DD) {
        const int t = threadIdx.x;
        float v = 0.f;
#pragma unroll
        for (int wq = 0; wq < WAVES; ++wq) v += red[wq][t];
        out[b * DD + t] = v;
    }
}

extern "C" void kernel_launch(void* const* d_in, const int* in_sizes, int n_in,
                              void* d_out, int out_size, void* d_ws, size_t ws_size,
                              hipStream_t stream) {
    const float* x = (const float*)d_in[0];
    const float* w = (const float*)d_in[1];
    // d_in[2] (edge_index) and d_in[3] (batch) are dead w.r.t. the output.
    float* out = (float*)d_out;
    (void)d_ws; (void)ws_size;

    topk_pool_fused<<<BG, 512, 0, stream>>>(x, w, out);   // 256 blocks = 1/CU
}